// Round 2
// baseline (201.617 us; speedup 1.0000x reference)
//
#include <hip/hip_runtime.h>
#include <hip/hip_bf16.h>

// ---------- types / helpers ----------
typedef __attribute__((ext_vector_type(8))) short bf16x8;   // 8 bf16 = 4 VGPRs
typedef __attribute__((ext_vector_type(4))) short bf16x4;
typedef __attribute__((ext_vector_type(4))) float f32x4;

__device__ __forceinline__ short f2bf(float f) {
    unsigned u = __float_as_uint(f);
    u += 0x7fff + ((u >> 16) & 1);          // round-to-nearest-even
    return (short)(u >> 16);
}
__device__ __forceinline__ float bf2f(short s) {
    return __uint_as_float(((unsigned)(unsigned short)s) << 16);
}
__device__ __forceinline__ unsigned pk_bf16(float lo, float hi) {
    __hip_bfloat162 t = __float22bfloat162_rn(make_float2(lo, hi));
    unsigned u;
    __builtin_memcpy(&u, &t, 4);
    return u;
}

#define GLOAD_LDS16(gp, lp)                                                            \
    __builtin_amdgcn_global_load_lds(                                                  \
        (const __attribute__((address_space(1))) unsigned*)(gp),                       \
        (__attribute__((address_space(3))) unsigned*)(lp), 16, 0, 0)

#define QK_SCALE 0.180336879f   // (1/sqrt(64)) * log2(e), folded into q at GEMM1
#define MFMA16(a, b, c) __builtin_amdgcn_mfma_f32_16x16x32_bf16((a), (b), (c), 0, 0, 0)

// ---------- fused prep: enc->bf16, biases->bf16, Wa/Wo -> transposed bf16 ----------
__device__ __forceinline__ void tcvt_tile(const float* __restrict__ W, short* __restrict__ Wt,
                                          int K, int N, int bx, int by, int t,
                                          short (*tile)[72]) {
    const int k0 = by * 64, n0 = bx * 64;
    #pragma unroll
    for (int jj = 0; jj < 4; ++jj) {
        int row = jj * 16 + (t >> 4);
        int col = (t & 15) * 4;
        f32x4 v = *(const f32x4*)&W[(size_t)(k0 + row) * N + n0 + col];
        bf16x4 b = {f2bf(v.x), f2bf(v.y), f2bf(v.z), f2bf(v.w)};
        *(bf16x4*)&tile[row][col] = b;
    }
    __syncthreads();
    const int nr = t >> 2, kc = (t & 3) * 16;
    bf16x8 o0, o1;
    #pragma unroll
    for (int j = 0; j < 8; ++j) { o0[j] = tile[kc + j][nr]; o1[j] = tile[kc + 8 + j][nr]; }
    short* dst = &Wt[(size_t)(n0 + nr) * K + k0 + kc];
    *(bf16x8*)dst = o0;
    *(bf16x8*)(dst + 8) = o1;
}

__global__ __launch_bounds__(256) void prep_kernel(
    const float* __restrict__ enc, const float* __restrict__ Wa,
    const float* __restrict__ ba, const float* __restrict__ Wo,
    const float* __restrict__ bo, short* __restrict__ Abf,
    short* __restrict__ WtA, short* __restrict__ bbA,
    short* __restrict__ WtO, short* __restrict__ bbO)
{
    __shared__ alignas(16) short tile[64][72];
    const int id = blockIdx.x, t = threadIdx.x;
    if (id < 2048) {
        const int i = id * 2048 + t * 8;
        f32x4 a = *(const f32x4*)&enc[i];
        f32x4 b = *(const f32x4*)&enc[i + 4];
        bf16x8 o = {f2bf(a.x), f2bf(a.y), f2bf(a.z), f2bf(a.w),
                    f2bf(b.x), f2bf(b.y), f2bf(b.z), f2bf(b.w)};
        *(bf16x8*)&Abf[i] = o;
    } else if (id == 2048) {
        for (int j = t * 8; j < 3072; j += 2048) {
            f32x4 a = *(const f32x4*)&ba[j];
            f32x4 b = *(const f32x4*)&ba[j + 4];
            bf16x8 o = {f2bf(a.x), f2bf(a.y), f2bf(a.z), f2bf(a.w),
                        f2bf(b.x), f2bf(b.y), f2bf(b.z), f2bf(b.w)};
            *(bf16x8*)&bbA[j] = o;
        }
    } else if (id == 2049) {
        if (t < 128) {
            const int j = t * 8;
            f32x4 a = *(const f32x4*)&bo[j];
            f32x4 b = *(const f32x4*)&bo[j + 4];
            bf16x8 o = {f2bf(a.x), f2bf(a.y), f2bf(a.z), f2bf(a.w),
                        f2bf(b.x), f2bf(b.y), f2bf(b.z), f2bf(b.w)};
            *(bf16x8*)&bbO[j] = o;
        }
        __syncthreads();
    } else if (id < 2818) {
        const int lid = id - 2050;
        tcvt_tile(Wa, WtA, 1024, 3072, lid % 48, lid / 48, t, tile);
    } else {
        const int lid = id - 2818;
        tcvt_tile(Wo, WtO, 1024, 1024, lid % 16, lid / 16, t, tile);
    }
}

// ---------- m97-style BT GEMM: C = A @ Bt^T + bias ----------
// SPLIT3: N=3072, col group g=n0>>10 routes to Q (row-major, scaled) or
// directly to Kx/Vx in attn fragment order via an LDS-staged, XOR-swizzled
// epilogue (fully coalesced 16B stores; kills the 2.4x write-amp + RMW
// fetches of the old 2B scatter, and deletes the fragprep kernel).
// Else: single output (fp32 if F32OUT), original epilogue.
template<int BN, bool F32OUT, bool SPLIT3>
__global__ __launch_bounds__(256) void gemm_bt(
    const short* __restrict__ A, const short* __restrict__ Bt,
    const short* __restrict__ bias, void* __restrict__ C,
    short* __restrict__ Kw, short* __restrict__ Vw, int M, int N, int K)
{
    __shared__ alignas(16) short As[128 * 32];
    __shared__ alignas(16) short Bs[BN * 32];
    __shared__ alignas(16) short Ct[SPLIT3 ? 128 * 128 : 1];

    const int tid = threadIdx.x, w = tid >> 6, lane = tid & 63;
    const int quad = lane >> 4, l16 = lane & 15;
    constexpr int MT = (BN == 128) ? 4 : 2;
    const int wm = (BN == 128) ? (w >> 1) : w;
    const int wn = (BN == 128) ? (w & 1) : 0;
    const int m0 = blockIdx.y * 128, n0 = blockIdx.x * BN;
    const int srow = lane >> 2, scol = (lane & 3) * 8;

    f32x4 acc[MT][4] = {};

    for (int k0 = 0; k0 < K; k0 += 32) {
        __syncthreads();
        #pragma unroll
        for (int jj = 0; jj < 2; ++jj) {
            const int rb = w * 32 + jj * 16;
            GLOAD_LDS16(&A[(size_t)(m0 + rb + srow) * K + k0 + scol], &As[rb * 32]);
        }
        if (BN == 128) {
            #pragma unroll
            for (int jj = 0; jj < 2; ++jj) {
                const int rb = w * 32 + jj * 16;
                GLOAD_LDS16(&Bt[(size_t)(n0 + rb + srow) * K + k0 + scol], &Bs[rb * 32]);
            }
        } else {
            const int rb = w * 16;
            GLOAD_LDS16(&Bt[(size_t)(n0 + rb + srow) * K + k0 + scol], &Bs[rb * 32]);
        }
        __syncthreads();
        bf16x8 af[MT], bfr[4];
        #pragma unroll
        for (int i = 0; i < MT; ++i)
            af[i] = *(const bf16x8*)&As[(wm * (MT * 16) + i * 16 + l16) * 32 + quad * 8];
        #pragma unroll
        for (int i = 0; i < 4; ++i)
            bfr[i] = *(const bf16x8*)&Bs[(wn * 64 + i * 16 + l16) * 32 + quad * 8];
        #pragma unroll
        for (int mt = 0; mt < MT; ++mt)
            #pragma unroll
            for (int nt = 0; nt < 4; ++nt)
                acc[mt][nt] = MFMA16(af[mt], bfr[nt], acc[mt][nt]);
    }

    if (SPLIT3) {
        const int g = n0 >> 10;                     // 0=q,1=k,2=v (block-uniform)
        const int lc0 = n0 & 1023;
        // ---- stage 128x128 C tile into LDS, 16B-chunk XOR swizzle ----
        if (g < 2) {
            // row-major: Ct[row][((col>>3) ^ (row&15))*8 + (col&7)]
            #pragma unroll
            for (int nt = 0; nt < 4; ++nt) {
                const int col = wn * 64 + nt * 16 + l16;
                const float bv = bf2f(bias[n0 + col]);
                const int chunk = col >> 3, wi = col & 7;
                #pragma unroll
                for (int mt = 0; mt < 4; ++mt) {
                    const int rbase = wm * 64 + mt * 16 + quad * 4;
                    #pragma unroll
                    for (int r = 0; r < 4; ++r) {
                        const int row = rbase + r;
                        float v = acc[mt][nt][r] + bv;
                        if (g == 0) v *= QK_SCALE;
                        Ct[row * 128 + (((chunk ^ (row & 15)) << 3) | wi)] = f2bf(v);
                    }
                }
            }
        } else {
            // transposed [d][key]: Ct[d][((key>>3) ^ (d&15))*8 + (key&7)],
            // 4 contiguous keys per acc reg quad -> one 8B store
            #pragma unroll
            for (int nt = 0; nt < 4; ++nt) {
                const int d = wn * 64 + nt * 16 + l16;
                const float bv = bf2f(bias[n0 + d]);
                const int dsw = d & 15;
                #pragma unroll
                for (int mt = 0; mt < 4; ++mt) {
                    const int key0 = wm * 64 + mt * 16 + quad * 4;
                    bf16x4 p = {f2bf(acc[mt][nt][0] + bv), f2bf(acc[mt][nt][1] + bv),
                                f2bf(acc[mt][nt][2] + bv), f2bf(acc[mt][nt][3] + bv)};
                    *(bf16x4*)&Ct[d * 128 + ((((key0 >> 3) ^ dsw) << 3) | (key0 & 7))] = p;
                }
            }
        }
        __syncthreads();
        // ---- coalesced writeout ----
        const int batch = m0 >> 11;
        const int kc0 = (m0 & 2047) >> 6;           // even; tile covers kc0, kc0+1
        const int head0 = lc0 >> 6;                 // even; tile covers head0, head0+1
        if (g == 0) {
            short* dst = (short*)C;                 // Qw, row-major [4096][1024]
            #pragma unroll
            for (int i = 0; i < 8; ++i) {
                const int idx = i * 256 + tid;      // 0..2047
                const int row = idx >> 4, chunk = idx & 15;
                bf16x8 v = *(const bf16x8*)&Ct[row * 128 + ((chunk ^ (row & 15)) << 3)];
                *(bf16x8*)&dst[(size_t)(m0 + row) * 1024 + lc0 + chunk * 8] = v;
            }
        } else if (g == 1) {
            // Kx[bh][kc][c=(s*2+h2)*64+lane][j] = K[kc*64+s*16+l16][h2*32+quad*8+j]
            #pragma unroll
            for (int i = 0; i < 8; ++i) {
                const int idx = i * 256 + tid;
                const int qd = idx >> 9, c = idx & 511;
                const int kcL = qd >> 1, headL = qd & 1;
                const int s = c >> 7, h2 = (c >> 6) & 1;
                const int l16c = c & 15, quadc = (c >> 4) & 3;
                const int row = kcL * 64 + s * 16 + l16c;
                const int colc = headL * 8 + h2 * 4 + quadc;
                bf16x8 v = *(const bf16x8*)&Ct[row * 128 + ((colc ^ (row & 15)) << 3)];
                const int bh = batch * 16 + head0 + headL, kc = kc0 + kcL;
                *(bf16x8*)&Kw[((size_t)(bh * 32 + kc) * 512 + c) * 8] = v;
            }
        } else {
            // Vx[bh][kc][c=(h2*4+dt)*64+lane][j] = V[kc*64+h2*32+quad*8+j][dt*16+l16]
            #pragma unroll
            for (int i = 0; i < 8; ++i) {
                const int idx = i * 256 + tid;
                const int qd = idx >> 9, c = idx & 511;
                const int kcL = qd >> 1, headL = qd & 1;
                const int h2 = c >> 8, dt = (c >> 6) & 3;
                const int l16c = c & 15, quadc = (c >> 4) & 3;
                const int d = headL * 64 + dt * 16 + l16c;
                const int keyc = kcL * 8 + h2 * 4 + quadc;
                bf16x8 v = *(const bf16x8*)&Ct[d * 128 + ((keyc ^ (d & 15)) << 3)];
                const int bh = batch * 16 + head0 + headL, kc = kc0 + kcL;
                *(bf16x8*)&Vw[((size_t)(bh * 32 + kc) * 512 + c) * 8] = v;
            }
        }
    } else {
        #pragma unroll
        for (int nt = 0; nt < 4; ++nt) {
            const int col = n0 + wn * 64 + nt * 16 + l16;
            const float bv = bf2f(bias[col]);
            #pragma unroll
            for (int mt = 0; mt < MT; ++mt) {
                const int row = m0 + wm * (MT * 16) + mt * 16 + quad * 4;
                #pragma unroll
                for (int r = 0; r < 4; ++r) {
                    float v = acc[mt][nt][r] + bv;
                    if (F32OUT) ((float*)C)[(size_t)(row + r) * N + col] = v;
                    else        ((short*)C)[(size_t)(row + r) * N + col] = f2bf(v);
                }
            }
        }
    }
}

// ---------- barrier-light causal flash attention, split-K for occupancy ----------
// 4 waves: wave-half h in {0,1} handles kc steps of parity h for the same
// paired {tA, 63-tA} 32-row q tiles; partials merged through LDS (static-max
// softmax => O = O0+O1, l = l0+l1).
__global__ __launch_bounds__(256) void attn_kernel(
    const short* __restrict__ Qw, const short* __restrict__ Kx,
    const short* __restrict__ Vx, short* __restrict__ comb)
{
    __shared__ alignas(16) short Ps[4][2][16 * 72];   // [wave][tile A/B]
    __shared__ alignas(16) float cbuf[2][2][64][16];  // [w][tile][lane][dt*4+r]
    __shared__ float clacc[2][2][64];                 // [w][tile][lane]

    const int tid = threadIdx.x, w4 = tid >> 6, lane = tid & 63;
    const int w = w4 & 1;          // 16-row q sub-tile within the 32-row tiles
    const int h = w4 >> 1;         // key-parity half
    const int quad = lane >> 4, l16 = lane & 15;
    const int bh = blockIdx.x;
    const int tA = blockIdx.y, tB = 63 - tA;
    const int batch = bh >> 4, head = bh & 15;
    const size_t rowbase = (size_t)batch * 2048;
    const int hcol = head * 64;
    const int q0A = tA * 32 + w * 16, q0B = tB * 32 + w * 16;
    const int diagA = tA >> 1, diagB = tB >> 1;
    const short* Kxbh = Kx + (size_t)bh * 131072;
    const short* Vxbh = Vx + (size_t)bh * 131072;
    const int lofs = lane * 8;
    short* pwA = &Ps[w4][0][0];
    short* pwB = &Ps[w4][1][0];

    // Q fragments (B-operand: q = l16, d = quad*8+j (+32))
    bf16x8 qfA[2], qfB[2];
    {
        const short* pa = &Qw[(rowbase + q0A + l16) * 1024 + hcol];
        const short* pb = &Qw[(rowbase + q0B + l16) * 1024 + hcol];
        qfA[0] = *(const bf16x8*)(pa + quad * 8);
        qfA[1] = *(const bf16x8*)(pa + 32 + quad * 8);
        qfB[0] = *(const bf16x8*)(pb + quad * 8);
        qfB[1] = *(const bf16x8*)(pb + 32 + quad * 8);
    }

    f32x4 otA[4] = {}, otB[4] = {};
    float laccA = 0.f, laccB = 0.f;

    // preload K fragments for this half's first step (kc = h)
    bf16x8 kf[4][2];
    {
        const short* kb0 = Kxbh + (size_t)h * 4096;
        #pragma unroll
        for (int s = 0; s < 4; ++s) {
            kf[s][0] = *(const bf16x8*)&kb0[(s * 2 + 0) * 512 + lofs];
            kf[s][1] = *(const bf16x8*)&kb0[(s * 2 + 1) * 512 + lofs];
        }
    }

    for (int kc = h; kc <= diagB; kc += 2) {
        const bool actA = (kc <= diagA);
        const int key0 = kc * 64;

        // V fragments for current step — issued early, consumed at step end
        const short* vb = Vxbh + (size_t)kc * 4096;
        bf16x8 vf[2][4];
        #pragma unroll
        for (int hh = 0; hh < 2; ++hh)
            #pragma unroll
            for (int dt = 0; dt < 4; ++dt)
                vf[hh][dt] = *(const bf16x8*)&vb[(hh * 4 + dt) * 512 + lofs];

        // ---- QK (S^T = K.Q^T): consumes kf ----
        f32x4 svA[4], svB[4];
        #pragma unroll
        for (int s = 0; s < 4; ++s) {
            f32x4 a = {0.f, 0.f, 0.f, 0.f};
            a = MFMA16(kf[s][0], qfB[0], a);
            a = MFMA16(kf[s][1], qfB[1], a);
            svB[s] = a;
            if (actA) {
                f32x4 b = {0.f, 0.f, 0.f, 0.f};
                b = MFMA16(kf[s][0], qfA[0], b);
                b = MFMA16(kf[s][1], qfA[1], b);
                svA[s] = b;
            }
        }

        // ---- prefetch this half's next K step (off critical path) ----
        if (kc + 2 <= diagB) {
            const short* kb = Kxbh + (size_t)(kc + 2) * 4096;
            #pragma unroll
            for (int s = 0; s < 4; ++s) {
                kf[s][0] = *(const bf16x8*)&kb[(s * 2 + 0) * 512 + lofs];
                kf[s][1] = *(const bf16x8*)&kb[(s * 2 + 1) * 512 + lofs];
            }
        }

        // ---- softmax + P^T -> per-wave LDS ----
        if (kc == diagB) {
            const int qq = q0B + l16;
            #pragma unroll
            for (int s = 0; s < 4; ++s) {
                const int keyb = key0 + s * 16 + quad * 4;
                #pragma unroll
                for (int r = 0; r < 4; ++r)
                    svB[s][r] = (keyb + r <= qq) ? svB[s][r] : -1e30f;
            }
        }
        #pragma unroll
        for (int s = 0; s < 4; ++s) {
            #pragma unroll
            for (int r = 0; r < 4; ++r) svB[s][r] = exp2f(svB[s][r]);
            laccB += (svB[s][0] + svB[s][1]) + (svB[s][2] + svB[s][3]);
            *(unsigned*)&pwB[l16 * 72 + s * 16 + quad * 4]     = pk_bf16(svB[s][0], svB[s][1]);
            *(unsigned*)&pwB[l16 * 72 + s * 16 + quad * 4 + 2] = pk_bf16(svB[s][2], svB[s][3]);
        }
        if (actA) {
            if (kc == diagA) {
                const int qq = q0A + l16;
                #pragma unroll
                for (int s = 0; s < 4; ++s) {
                    const int keyb = key0 + s * 16 + quad * 4;
                    #pragma unroll
                    for (int r = 0; r < 4; ++r)
                        svA[s][r] = (keyb + r <= qq) ? svA[s][r] : -1e30f;
                }
            }
            #pragma unroll
            for (int s = 0; s < 4; ++s) {
                #pragma unroll
                for (int r = 0; r < 4; ++r) svA[s][r] = exp2f(svA[s][r]);
                laccA += (svA[s][0] + svA[s][1]) + (svA[s][2] + svA[s][3]);
                *(unsigned*)&pwA[l16 * 72 + s * 16 + quad * 4]     = pk_bf16(svA[s][0], svA[s][1]);
                *(unsigned*)&pwA[l16 * 72 + s * 16 + quad * 4 + 2] = pk_bf16(svA[s][2], svA[s][3]);
            }
        }

        // ---- PV (O^T += V^T.P^T); wave-internal DS is in-order ----
        {
            bf16x8 pfB0 = *(const bf16x8*)&pwB[l16 * 72 + quad * 8];
            bf16x8 pfB1 = *(const bf16x8*)&pwB[l16 * 72 + 32 + quad * 8];
            #pragma unroll
            for (int dt = 0; dt < 4; ++dt) {
                otB[dt] = MFMA16(vf[0][dt], pfB0, otB[dt]);
                otB[dt] = MFMA16(vf[1][dt], pfB1, otB[dt]);
            }
            if (actA) {
                bf16x8 pfA0 = *(const bf16x8*)&pwA[l16 * 72 + quad * 8];
                bf16x8 pfA1 = *(const bf16x8*)&pwA[l16 * 72 + 32 + quad * 8];
                #pragma unroll
                for (int dt = 0; dt < 4; ++dt) {
                    otA[dt] = MFMA16(vf[0][dt], pfA0, otA[dt]);
                    otA[dt] = MFMA16(vf[1][dt], pfA1, otA[dt]);
                }
            }
        }
    }

    // ---- combine the two key-parity halves (static-max: plain sums) ----
    __syncthreads();
    if (h == 1) {
        #pragma unroll
        for (int dt = 0; dt < 4; ++dt) {
            *(f32x4*)&cbuf[w][0][lane][dt * 4] = otA[dt];
            *(f32x4*)&cbuf[w][1][lane][dt * 4] = otB[dt];
        }
        clacc[w][0][lane] = laccA;
        clacc[w][1][lane] = laccB;
    }
    __syncthreads();
    if (h == 0) {
        #pragma unroll
        for (int dt = 0; dt < 4; ++dt) {
            otA[dt] += *(const f32x4*)&cbuf[w][0][lane][dt * 4];
            otB[dt] += *(const f32x4*)&cbuf[w][1][lane][dt * 4];
        }
        laccA += clacc[w][0][lane];
        laccB += clacc[w][1][lane];

        // ---- l reduction (lanes sharing l16 across quads) + epilogue ----
        laccA += __shfl_xor(laccA, 16);
        laccA += __shfl_xor(laccA, 32);
        laccB += __shfl_xor(laccB, 16);
        laccB += __shfl_xor(laccB, 32);
        const float invA = 1.0f / laccA, invB = 1.0f / laccB;

        #pragma unroll
        for (int dt = 0; dt < 4; ++dt) {
            *(unsigned*)&pwA[l16 * 72 + dt * 16 + quad * 4]     = pk_bf16(otA[dt][0] * invA, otA[dt][1] * invA);
            *(unsigned*)&pwA[l16 * 72 + dt * 16 + quad * 4 + 2] = pk_bf16(otA[dt][2] * invA, otA[dt][3] * invA);
            *(unsigned*)&pwB[l16 * 72 + dt * 16 + quad * 4]     = pk_bf16(otB[dt][0] * invB, otB[dt][1] * invB);
            *(unsigned*)&pwB[l16 * 72 + dt * 16 + quad * 4 + 2] = pk_bf16(otB[dt][2] * invB, otB[dt][3] * invB);
        }
        {
            const int qr = lane >> 2, dc = (lane & 3) * 16;
            bf16x8 a0 = *(const bf16x8*)&pwA[qr * 72 + dc];
            bf16x8 a1 = *(const bf16x8*)&pwA[qr * 72 + dc + 8];
            short* dstA = &comb[(rowbase + q0A + qr) * 1024 + hcol + dc];
            *(bf16x8*)dstA = a0;
            *(bf16x8*)(dstA + 8) = a1;
            bf16x8 b0 = *(const bf16x8*)&pwB[qr * 72 + dc];
            bf16x8 b1 = *(const bf16x8*)&pwB[qr * 72 + dc + 8];
            short* dstB = &comb[(rowbase + q0B + qr) * 1024 + hcol + dc];
            *(bf16x8*)dstB = b0;
            *(bf16x8*)(dstB + 8) = b1;
        }
    }
}

// ---------- launch ----------
extern "C" void kernel_launch(void* const* d_in, const int* in_sizes, int n_in,
                              void* d_out, int out_size, void* d_ws, size_t ws_size,
                              hipStream_t stream)
{
    const float* enc = (const float*)d_in[0];
    const float* Wa  = (const float*)d_in[1];
    const float* ba  = (const float*)d_in[2];
    const float* Wo  = (const float*)d_in[3];
    const float* bo  = (const float*)d_in[4];
    float* out = (float*)d_out;

    // layout (41 MB peak):
    // [0,8)   Abf (dead after gemm1) -> comb
    // [8,10)  WtO    [10,11) biases
    // [11,17) WtA    [17,25) Kx    [25,33) Vx    [33,41) Qw
    char* ws = (char*)d_ws;
    short* Abf  = (short*)ws;
    short* comb = (short*)ws;
    short* WtO  = (short*)(ws + ((size_t)8 << 20));
    short* bbA  = (short*)(ws + ((size_t)10 << 20));
    short* bbO  = (short*)(ws + ((size_t)10 << 20) + 16384);
    short* WtA  = (short*)(ws + ((size_t)11 << 20));
    short* Kx   = (short*)(ws + ((size_t)17 << 20));
    short* Vx   = (short*)(ws + ((size_t)25 << 20));
    short* Qw   = (short*)(ws + ((size_t)33 << 20));

    prep_kernel<<<3074, 256, 0, stream>>>(enc, Wa, ba, Wo, bo, Abf, WtA, bbA, WtO, bbO);
    gemm_bt<128, false, true><<<dim3(24, 32), 256, 0, stream>>>(
        Abf, WtA, bbA, Qw, Kx, Vx, 4096, 3072, 1024);
    attn_kernel<<<dim3(32, 32), 256, 0, stream>>>(Qw, Kx, Vx, comb);
    gemm_bt<64, true, false><<<dim3(16, 32), 256, 0, stream>>>(
        comb, WtO, bbO, out, nullptr, nullptr, 4096, 1024, 1024);
}

// Round 3
// 187.496 us; speedup vs baseline: 1.0753x; 1.0753x over previous
//
#include <hip/hip_runtime.h>
#include <hip/hip_bf16.h>

// ---------- types / helpers ----------
typedef __attribute__((ext_vector_type(8))) short bf16x8;   // 8 bf16 = 4 VGPRs
typedef __attribute__((ext_vector_type(4))) short bf16x4;
typedef __attribute__((ext_vector_type(4))) float f32x4;

__device__ __forceinline__ short f2bf(float f) {
    unsigned u = __float_as_uint(f);
    u += 0x7fff + ((u >> 16) & 1);          // round-to-nearest-even
    return (short)(u >> 16);
}
__device__ __forceinline__ float bf2f(short s) {
    return __uint_as_float(((unsigned)(unsigned short)s) << 16);
}
__device__ __forceinline__ unsigned pk_bf16(float lo, float hi) {
    __hip_bfloat162 t = __float22bfloat162_rn(make_float2(lo, hi));
    unsigned u;
    __builtin_memcpy(&u, &t, 4);
    return u;
}

#define GLOAD_LDS16(gp, lp)                                                            \
    __builtin_amdgcn_global_load_lds(                                                  \
        (const __attribute__((address_space(1))) unsigned*)(gp),                       \
        (__attribute__((address_space(3))) unsigned*)(lp), 16, 0, 0)

#define QK_SCALE 0.180336879f   // (1/sqrt(64)) * log2(e), folded into q at GEMM1
#define MFMA16(a, b, c) __builtin_amdgcn_mfma_f32_16x16x32_bf16((a), (b), (c), 0, 0, 0)

// ---------- fused prep: enc->bf16, biases->bf16, Wa/Wo -> transposed bf16 ----------
__device__ __forceinline__ void tcvt_tile(const float* __restrict__ W, short* __restrict__ Wt,
                                          int K, int N, int bx, int by, int t,
                                          short (*tile)[72]) {
    const int k0 = by * 64, n0 = bx * 64;
    #pragma unroll
    for (int jj = 0; jj < 4; ++jj) {
        int row = jj * 16 + (t >> 4);
        int col = (t & 15) * 4;
        f32x4 v = *(const f32x4*)&W[(size_t)(k0 + row) * N + n0 + col];
        bf16x4 b = {f2bf(v.x), f2bf(v.y), f2bf(v.z), f2bf(v.w)};
        *(bf16x4*)&tile[row][col] = b;
    }
    __syncthreads();
    const int nr = t >> 2, kc = (t & 3) * 16;
    bf16x8 o0, o1;
    #pragma unroll
    for (int j = 0; j < 8; ++j) { o0[j] = tile[kc + j][nr]; o1[j] = tile[kc + 8 + j][nr]; }
    short* dst = &Wt[(size_t)(n0 + nr) * K + k0 + kc];
    *(bf16x8*)dst = o0;
    *(bf16x8*)(dst + 8) = o1;
}

__global__ __launch_bounds__(256) void prep_kernel(
    const float* __restrict__ enc, const float* __restrict__ Wa,
    const float* __restrict__ ba, const float* __restrict__ Wo,
    const float* __restrict__ bo, short* __restrict__ Abf,
    short* __restrict__ WtA, short* __restrict__ bbA,
    short* __restrict__ WtO, short* __restrict__ bbO)
{
    __shared__ alignas(16) short tile[64][72];
    const int id = blockIdx.x, t = threadIdx.x;
    if (id < 2048) {
        const int i = id * 2048 + t * 8;
        f32x4 a = *(const f32x4*)&enc[i];
        f32x4 b = *(const f32x4*)&enc[i + 4];
        bf16x8 o = {f2bf(a.x), f2bf(a.y), f2bf(a.z), f2bf(a.w),
                    f2bf(b.x), f2bf(b.y), f2bf(b.z), f2bf(b.w)};
        *(bf16x8*)&Abf[i] = o;
    } else if (id == 2048) {
        for (int j = t * 8; j < 3072; j += 2048) {
            f32x4 a = *(const f32x4*)&ba[j];
            f32x4 b = *(const f32x4*)&ba[j + 4];
            bf16x8 o = {f2bf(a.x), f2bf(a.y), f2bf(a.z), f2bf(a.w),
                        f2bf(b.x), f2bf(b.y), f2bf(b.z), f2bf(b.w)};
            *(bf16x8*)&bbA[j] = o;
        }
    } else if (id == 2049) {
        if (t < 128) {
            const int j = t * 8;
            f32x4 a = *(const f32x4*)&bo[j];
            f32x4 b = *(const f32x4*)&bo[j + 4];
            bf16x8 o = {f2bf(a.x), f2bf(a.y), f2bf(a.z), f2bf(a.w),
                        f2bf(b.x), f2bf(b.y), f2bf(b.z), f2bf(b.w)};
            *(bf16x8*)&bbO[j] = o;
        }
        __syncthreads();
    } else if (id < 2818) {
        const int lid = id - 2050;
        tcvt_tile(Wa, WtA, 1024, 3072, lid % 48, lid / 48, t, tile);
    } else {
        const int lid = id - 2818;
        tcvt_tile(Wo, WtO, 1024, 1024, lid % 16, lid / 16, t, tile);
    }
}

// ---------- BT GEMM, BK=64: C = A @ Bt^T + bias ----------
// Round-3 rewrite: BK 32->64 halves the barrier-drain count (the measured
// bottleneck: MfmaUtil 17%, occupancy-limited latency kernel). LDS [row][64]
// would be a 16-way bank conflict on ds_read_b128, so 16B chunks are
// XOR-swizzled by row (chunk ^= row&7): global source is pre-swizzled per
// lane (global_load_lds dest must stay linear), ds_read applies the same XOR.
// SPLIT3 epilogue (fragment-order coalesced Kx/Vx/Q writeout) reuses the
// As+Bs LDS as the 128x128 Ct buffer -> total LDS 32KB, occupancy restored.
template<int BN, bool F32OUT, bool SPLIT3>
__global__ __launch_bounds__(256) void gemm_bt(
    const short* __restrict__ A, const short* __restrict__ Bt,
    const short* __restrict__ bias, void* __restrict__ C,
    short* __restrict__ Kw, short* __restrict__ Vw, int M, int N, int K)
{
    __shared__ alignas(16) short LB[128 * 64 + BN * 64];
    short* As = LB;                  // [128][64] shorts, 16B chunks row-XOR-swizzled
    short* Bs = LB + 128 * 64;       // [BN][64]
    short* Ct = LB;                  // SPLIT3 epilogue: [128][128] (exactly 32KB)

    const int tid = threadIdx.x, w = tid >> 6, lane = tid & 63;
    const int quad = lane >> 4, l16 = lane & 15;
    constexpr int MT = (BN == 128) ? 4 : 2;
    const int wm = (BN == 128) ? (w >> 1) : w;
    const int wn = (BN == 128) ? (w & 1) : 0;
    const int m0 = blockIdx.y * 128, n0 = blockIdx.x * BN;
    // staging: one gload16 = 64 lanes x 16B = 8 rows x 128B
    const int srow = lane >> 3;                 // 0..7 within the 8-row chunk
    const int scol = ((lane & 7) ^ srow) * 8;   // pre-swizzled source chunk

    f32x4 acc[MT][4] = {};

    for (int k0 = 0; k0 < K; k0 += 64) {
        __syncthreads();
        #pragma unroll
        for (int jj = 0; jj < 4; ++jj) {
            const int rb = w * 32 + jj * 8;
            GLOAD_LDS16(&A[(size_t)(m0 + rb + srow) * K + k0 + scol], &As[rb * 64]);
        }
        if (BN == 128) {
            #pragma unroll
            for (int jj = 0; jj < 4; ++jj) {
                const int rb = w * 32 + jj * 8;
                GLOAD_LDS16(&Bt[(size_t)(n0 + rb + srow) * K + k0 + scol], &Bs[rb * 64]);
            }
        } else {
            #pragma unroll
            for (int jj = 0; jj < 2; ++jj) {
                const int rb = w * 16 + jj * 8;
                GLOAD_LDS16(&Bt[(size_t)(n0 + rb + srow) * K + k0 + scol], &Bs[rb * 64]);
            }
        }
        __syncthreads();
        #pragma unroll
        for (int half = 0; half < 2; ++half) {
            const int kc2 = half * 4 + quad;    // 16B chunk index 0..7
            bf16x8 af[MT], bfr[4];
            #pragma unroll
            for (int i = 0; i < MT; ++i) {
                const int row = wm * (MT * 16) + i * 16 + l16;
                af[i] = *(const bf16x8*)&As[row * 64 + ((kc2 ^ (row & 7)) << 3)];
            }
            #pragma unroll
            for (int i = 0; i < 4; ++i) {
                const int row = wn * 64 + i * 16 + l16;
                bfr[i] = *(const bf16x8*)&Bs[row * 64 + ((kc2 ^ (row & 7)) << 3)];
            }
            #pragma unroll
            for (int mt = 0; mt < MT; ++mt)
                #pragma unroll
                for (int nt = 0; nt < 4; ++nt)
                    acc[mt][nt] = MFMA16(af[mt], bfr[nt], acc[mt][nt]);
        }
    }

    if (SPLIT3) {
        const int g = n0 >> 10;                     // 0=q,1=k,2=v (block-uniform)
        const int lc0 = n0 & 1023;
        __syncthreads();                            // done reading As/Bs; reuse as Ct
        // ---- stage 128x128 C tile into LDS, 16B-chunk XOR swizzle ----
        if (g < 2) {
            // row-major: Ct[row][((col>>3) ^ (row&15))*8 + (col&7)]
            #pragma unroll
            for (int nt = 0; nt < 4; ++nt) {
                const int col = wn * 64 + nt * 16 + l16;
                const float bv = bf2f(bias[n0 + col]);
                const int chunk = col >> 3, wi = col & 7;
                #pragma unroll
                for (int mt = 0; mt < 4; ++mt) {
                    const int rbase = wm * 64 + mt * 16 + quad * 4;
                    #pragma unroll
                    for (int r = 0; r < 4; ++r) {
                        const int row = rbase + r;
                        float v = acc[mt][nt][r] + bv;
                        if (g == 0) v *= QK_SCALE;
                        Ct[row * 128 + (((chunk ^ (row & 15)) << 3) | wi)] = f2bf(v);
                    }
                }
            }
        } else {
            // transposed [d][key]: Ct[d][((key>>3) ^ (d&15))*8 + (key&7)],
            // 4 contiguous keys per acc reg quad -> one 8B store
            #pragma unroll
            for (int nt = 0; nt < 4; ++nt) {
                const int d = wn * 64 + nt * 16 + l16;
                const float bv = bf2f(bias[n0 + d]);
                const int dsw = d & 15;
                #pragma unroll
                for (int mt = 0; mt < 4; ++mt) {
                    const int key0 = wm * 64 + mt * 16 + quad * 4;
                    bf16x4 p = {f2bf(acc[mt][nt][0] + bv), f2bf(acc[mt][nt][1] + bv),
                                f2bf(acc[mt][nt][2] + bv), f2bf(acc[mt][nt][3] + bv)};
                    *(bf16x4*)&Ct[d * 128 + ((((key0 >> 3) ^ dsw) << 3) | (key0 & 7))] = p;
                }
            }
        }
        __syncthreads();
        // ---- coalesced writeout ----
        const int batch = m0 >> 11;
        const int kc0 = (m0 & 2047) >> 6;           // even; tile covers kc0, kc0+1
        const int head0 = lc0 >> 6;                 // even; tile covers head0, head0+1
        if (g == 0) {
            short* dst = (short*)C;                 // Qw, row-major [4096][1024]
            #pragma unroll
            for (int i = 0; i < 8; ++i) {
                const int idx = i * 256 + tid;      // 0..2047
                const int row = idx >> 4, chunk = idx & 15;
                bf16x8 v = *(const bf16x8*)&Ct[row * 128 + ((chunk ^ (row & 15)) << 3)];
                *(bf16x8*)&dst[(size_t)(m0 + row) * 1024 + lc0 + chunk * 8] = v;
            }
        } else if (g == 1) {
            // Kx[bh][kc][c=(s*2+h2)*64+lane][j] = K[kc*64+s*16+l16][h2*32+quad*8+j]
            #pragma unroll
            for (int i = 0; i < 8; ++i) {
                const int idx = i * 256 + tid;
                const int qd = idx >> 9, c = idx & 511;
                const int kcL = qd >> 1, headL = qd & 1;
                const int s = c >> 7, h2 = (c >> 6) & 1;
                const int l16c = c & 15, quadc = (c >> 4) & 3;
                const int row = kcL * 64 + s * 16 + l16c;
                const int colc = headL * 8 + h2 * 4 + quadc;
                bf16x8 v = *(const bf16x8*)&Ct[row * 128 + ((colc ^ (row & 15)) << 3)];
                const int bh = batch * 16 + head0 + headL, kc = kc0 + kcL;
                *(bf16x8*)&Kw[((size_t)(bh * 32 + kc) * 512 + c) * 8] = v;
            }
        } else {
            // Vx[bh][kc][c=(h2*4+dt)*64+lane][j] = V[kc*64+h2*32+quad*8+j][dt*16+l16]
            #pragma unroll
            for (int i = 0; i < 8; ++i) {
                const int idx = i * 256 + tid;
                const int qd = idx >> 9, c = idx & 511;
                const int kcL = qd >> 1, headL = qd & 1;
                const int h2 = c >> 8, dt = (c >> 6) & 3;
                const int l16c = c & 15, quadc = (c >> 4) & 3;
                const int d = headL * 64 + dt * 16 + l16c;
                const int keyc = kcL * 8 + h2 * 4 + quadc;
                bf16x8 v = *(const bf16x8*)&Ct[d * 128 + ((keyc ^ (d & 15)) << 3)];
                const int bh = batch * 16 + head0 + headL, kc = kc0 + kcL;
                *(bf16x8*)&Vw[((size_t)(bh * 32 + kc) * 512 + c) * 8] = v;
            }
        }
    } else {
        #pragma unroll
        for (int nt = 0; nt < 4; ++nt) {
            const int col = n0 + wn * 64 + nt * 16 + l16;
            const float bv = bf2f(bias[col]);
            #pragma unroll
            for (int mt = 0; mt < MT; ++mt) {
                const int row = m0 + wm * (MT * 16) + mt * 16 + quad * 4;
                #pragma unroll
                for (int r = 0; r < 4; ++r) {
                    float v = acc[mt][nt][r] + bv;
                    if (F32OUT) ((float*)C)[(size_t)(row + r) * N + col] = v;
                    else        ((short*)C)[(size_t)(row + r) * N + col] = f2bf(v);
                }
            }
        }
    }
}

// ---------- barrier-light causal flash attention, split-K for occupancy ----------
// 4 waves: wave-half h in {0,1} handles kc steps of parity h for the same
// paired {tA, 63-tA} 32-row q tiles; partials merged through LDS (static-max
// softmax => O = O0+O1, l = l0+l1).
__global__ __launch_bounds__(256) void attn_kernel(
    const short* __restrict__ Qw, const short* __restrict__ Kx,
    const short* __restrict__ Vx, short* __restrict__ comb)
{
    __shared__ alignas(16) short Ps[4][2][16 * 72];   // [wave][tile A/B]
    __shared__ alignas(16) float cbuf[2][2][64][16];  // [w][tile][lane][dt*4+r]
    __shared__ float clacc[2][2][64];                 // [w][tile][lane]

    const int tid = threadIdx.x, w4 = tid >> 6, lane = tid & 63;
    const int w = w4 & 1;          // 16-row q sub-tile within the 32-row tiles
    const int h = w4 >> 1;         // key-parity half
    const int quad = lane >> 4, l16 = lane & 15;
    const int bh = blockIdx.x;
    const int tA = blockIdx.y, tB = 63 - tA;
    const int batch = bh >> 4, head = bh & 15;
    const size_t rowbase = (size_t)batch * 2048;
    const int hcol = head * 64;
    const int q0A = tA * 32 + w * 16, q0B = tB * 32 + w * 16;
    const int diagA = tA >> 1, diagB = tB >> 1;
    const short* Kxbh = Kx + (size_t)bh * 131072;
    const short* Vxbh = Vx + (size_t)bh * 131072;
    const int lofs = lane * 8;
    short* pwA = &Ps[w4][0][0];
    short* pwB = &Ps[w4][1][0];

    // Q fragments (B-operand: q = l16, d = quad*8+j (+32))
    bf16x8 qfA[2], qfB[2];
    {
        const short* pa = &Qw[(rowbase + q0A + l16) * 1024 + hcol];
        const short* pb = &Qw[(rowbase + q0B + l16) * 1024 + hcol];
        qfA[0] = *(const bf16x8*)(pa + quad * 8);
        qfA[1] = *(const bf16x8*)(pa + 32 + quad * 8);
        qfB[0] = *(const bf16x8*)(pb + quad * 8);
        qfB[1] = *(const bf16x8*)(pb + 32 + quad * 8);
    }

    f32x4 otA[4] = {}, otB[4] = {};
    float laccA = 0.f, laccB = 0.f;

    // preload K fragments for this half's first step (kc = h)
    bf16x8 kf[4][2];
    {
        const short* kb0 = Kxbh + (size_t)h * 4096;
        #pragma unroll
        for (int s = 0; s < 4; ++s) {
            kf[s][0] = *(const bf16x8*)&kb0[(s * 2 + 0) * 512 + lofs];
            kf[s][1] = *(const bf16x8*)&kb0[(s * 2 + 1) * 512 + lofs];
        }
    }

    for (int kc = h; kc <= diagB; kc += 2) {
        const bool actA = (kc <= diagA);
        const int key0 = kc * 64;

        // V fragments for current step — issued early, consumed at step end
        const short* vb = Vxbh + (size_t)kc * 4096;
        bf16x8 vf[2][4];
        #pragma unroll
        for (int hh = 0; hh < 2; ++hh)
            #pragma unroll
            for (int dt = 0; dt < 4; ++dt)
                vf[hh][dt] = *(const bf16x8*)&vb[(hh * 4 + dt) * 512 + lofs];

        // ---- QK (S^T = K.Q^T): consumes kf ----
        f32x4 svA[4], svB[4];
        #pragma unroll
        for (int s = 0; s < 4; ++s) {
            f32x4 a = {0.f, 0.f, 0.f, 0.f};
            a = MFMA16(kf[s][0], qfB[0], a);
            a = MFMA16(kf[s][1], qfB[1], a);
            svB[s] = a;
            if (actA) {
                f32x4 b = {0.f, 0.f, 0.f, 0.f};
                b = MFMA16(kf[s][0], qfA[0], b);
                b = MFMA16(kf[s][1], qfA[1], b);
                svA[s] = b;
            }
        }

        // ---- prefetch this half's next K step (off critical path) ----
        if (kc + 2 <= diagB) {
            const short* kb = Kxbh + (size_t)(kc + 2) * 4096;
            #pragma unroll
            for (int s = 0; s < 4; ++s) {
                kf[s][0] = *(const bf16x8*)&kb[(s * 2 + 0) * 512 + lofs];
                kf[s][1] = *(const bf16x8*)&kb[(s * 2 + 1) * 512 + lofs];
            }
        }

        // ---- softmax + P^T -> per-wave LDS ----
        if (kc == diagB) {
            const int qq = q0B + l16;
            #pragma unroll
            for (int s = 0; s < 4; ++s) {
                const int keyb = key0 + s * 16 + quad * 4;
                #pragma unroll
                for (int r = 0; r < 4; ++r)
                    svB[s][r] = (keyb + r <= qq) ? svB[s][r] : -1e30f;
            }
        }
        #pragma unroll
        for (int s = 0; s < 4; ++s) {
            #pragma unroll
            for (int r = 0; r < 4; ++r) svB[s][r] = exp2f(svB[s][r]);
            laccB += (svB[s][0] + svB[s][1]) + (svB[s][2] + svB[s][3]);
            *(unsigned*)&pwB[l16 * 72 + s * 16 + quad * 4]     = pk_bf16(svB[s][0], svB[s][1]);
            *(unsigned*)&pwB[l16 * 72 + s * 16 + quad * 4 + 2] = pk_bf16(svB[s][2], svB[s][3]);
        }
        if (actA) {
            if (kc == diagA) {
                const int qq = q0A + l16;
                #pragma unroll
                for (int s = 0; s < 4; ++s) {
                    const int keyb = key0 + s * 16 + quad * 4;
                    #pragma unroll
                    for (int r = 0; r < 4; ++r)
                        svA[s][r] = (keyb + r <= qq) ? svA[s][r] : -1e30f;
                }
            }
            #pragma unroll
            for (int s = 0; s < 4; ++s) {
                #pragma unroll
                for (int r = 0; r < 4; ++r) svA[s][r] = exp2f(svA[s][r]);
                laccA += (svA[s][0] + svA[s][1]) + (svA[s][2] + svA[s][3]);
                *(unsigned*)&pwA[l16 * 72 + s * 16 + quad * 4]     = pk_bf16(svA[s][0], svA[s][1]);
                *(unsigned*)&pwA[l16 * 72 + s * 16 + quad * 4 + 2] = pk_bf16(svA[s][2], svA[s][3]);
            }
        }

        // ---- PV (O^T += V^T.P^T); wave-internal DS is in-order ----
        {
            bf16x8 pfB0 = *(const bf16x8*)&pwB[l16 * 72 + quad * 8];
            bf16x8 pfB1 = *(const bf16x8*)&pwB[l16 * 72 + 32 + quad * 8];
            #pragma unroll
            for (int dt = 0; dt < 4; ++dt) {
                otB[dt] = MFMA16(vf[0][dt], pfB0, otB[dt]);
                otB[dt] = MFMA16(vf[1][dt], pfB1, otB[dt]);
            }
            if (actA) {
                bf16x8 pfA0 = *(const bf16x8*)&pwA[l16 * 72 + quad * 8];
                bf16x8 pfA1 = *(const bf16x8*)&pwA[l16 * 72 + 32 + quad * 8];
                #pragma unroll
                for (int dt = 0; dt < 4; ++dt) {
                    otA[dt] = MFMA16(vf[0][dt], pfA0, otA[dt]);
                    otA[dt] = MFMA16(vf[1][dt], pfA1, otA[dt]);
                }
            }
        }
    }

    // ---- combine the two key-parity halves (static-max: plain sums) ----
    __syncthreads();
    if (h == 1) {
        #pragma unroll
        for (int dt = 0; dt < 4; ++dt) {
            *(f32x4*)&cbuf[w][0][lane][dt * 4] = otA[dt];
            *(f32x4*)&cbuf[w][1][lane][dt * 4] = otB[dt];
        }
        clacc[w][0][lane] = laccA;
        clacc[w][1][lane] = laccB;
    }
    __syncthreads();
    if (h == 0) {
        #pragma unroll
        for (int dt = 0; dt < 4; ++dt) {
            otA[dt] += *(const f32x4*)&cbuf[w][0][lane][dt * 4];
            otB[dt] += *(const f32x4*)&cbuf[w][1][lane][dt * 4];
        }
        laccA += clacc[w][0][lane];
        laccB += clacc[w][1][lane];

        // ---- l reduction (lanes sharing l16 across quads) + epilogue ----
        laccA += __shfl_xor(laccA, 16);
        laccA += __shfl_xor(laccA, 32);
        laccB += __shfl_xor(laccB, 16);
        laccB += __shfl_xor(laccB, 32);
        const float invA = 1.0f / laccA, invB = 1.0f / laccB;

        #pragma unroll
        for (int dt = 0; dt < 4; ++dt) {
            *(unsigned*)&pwA[l16 * 72 + dt * 16 + quad * 4]     = pk_bf16(otA[dt][0] * invA, otA[dt][1] * invA);
            *(unsigned*)&pwA[l16 * 72 + dt * 16 + quad * 4 + 2] = pk_bf16(otA[dt][2] * invA, otA[dt][3] * invA);
            *(unsigned*)&pwB[l16 * 72 + dt * 16 + quad * 4]     = pk_bf16(otB[dt][0] * invB, otB[dt][1] * invB);
            *(unsigned*)&pwB[l16 * 72 + dt * 16 + quad * 4 + 2] = pk_bf16(otB[dt][2] * invB, otB[dt][3] * invB);
        }
        {
            const int qr = lane >> 2, dc = (lane & 3) * 16;
            bf16x8 a0 = *(const bf16x8*)&pwA[qr * 72 + dc];
            bf16x8 a1 = *(const bf16x8*)&pwA[qr * 72 + dc + 8];
            short* dstA = &comb[(rowbase + q0A + qr) * 1024 + hcol + dc];
            *(bf16x8*)dstA = a0;
            *(bf16x8*)(dstA + 8) = a1;
            bf16x8 b0 = *(const bf16x8*)&pwB[qr * 72 + dc];
            bf16x8 b1 = *(const bf16x8*)&pwB[qr * 72 + dc + 8];
            short* dstB = &comb[(rowbase + q0B + qr) * 1024 + hcol + dc];
            *(bf16x8*)dstB = b0;
            *(bf16x8*)(dstB + 8) = b1;
        }
    }
}

// ---------- launch ----------
extern "C" void kernel_launch(void* const* d_in, const int* in_sizes, int n_in,
                              void* d_out, int out_size, void* d_ws, size_t ws_size,
                              hipStream_t stream)
{
    const float* enc = (const float*)d_in[0];
    const float* Wa  = (const float*)d_in[1];
    const float* ba  = (const float*)d_in[2];
    const float* Wo  = (const float*)d_in[3];
    const float* bo  = (const float*)d_in[4];
    float* out = (float*)d_out;

    // layout (41 MB peak):
    // [0,8)   Abf (dead after gemm1) -> comb
    // [8,10)  WtO    [10,11) biases
    // [11,17) WtA    [17,25) Kx    [25,33) Vx    [33,41) Qw
    char* ws = (char*)d_ws;
    short* Abf  = (short*)ws;
    short* comb = (short*)ws;
    short* WtO  = (short*)(ws + ((size_t)8 << 20));
    short* bbA  = (short*)(ws + ((size_t)10 << 20));
    short* bbO  = (short*)(ws + ((size_t)10 << 20) + 16384);
    short* WtA  = (short*)(ws + ((size_t)11 << 20));
    short* Kx   = (short*)(ws + ((size_t)17 << 20));
    short* Vx   = (short*)(ws + ((size_t)25 << 20));
    short* Qw   = (short*)(ws + ((size_t)33 << 20));

    prep_kernel<<<3074, 256, 0, stream>>>(enc, Wa, ba, Wo, bo, Abf, WtA, bbA, WtO, bbO);
    gemm_bt<128, false, true><<<dim3(24, 32), 256, 0, stream>>>(
        Abf, WtA, bbA, Qw, Kx, Vx, 4096, 3072, 1024);
    attn_kernel<<<dim3(32, 32), 256, 0, stream>>>(Qw, Kx, Vx, comb);
    gemm_bt<64, true, false><<<dim3(16, 32), 256, 0, stream>>>(
        comb, WtO, bbO, out, nullptr, nullptr, 4096, 1024, 1024);
}